// Round 17
// baseline (103.789 us; speedup 1.0000x reference)
//
#include <hip/hip_runtime.h>

typedef unsigned short u16;
typedef __attribute__((ext_vector_type(8))) __bf16 bf16x8;
typedef __attribute__((ext_vector_type(4))) float f32x4;
typedef __attribute__((ext_vector_type(8))) u16 u16x8;

#define T_SEQ 2048
#define DIM   1024
#define HDIM  64
#define WIN   128
#define XN_EL (2 * T_SEQ * DIM)   // 4194304

#define AS1 __attribute__((address_space(1)))
#define AS3 __attribute__((address_space(3)))

__device__ __forceinline__ u16 f2bf(float f) {
  union { float f; unsigned u; } v; v.f = f;
  unsigned r = v.u + 0x7fffu + ((v.u >> 16) & 1u);  // RNE
  return (u16)(r >> 16);
}
__device__ __forceinline__ float bf2f(u16 u) {
  union { unsigned u; float f; } v; v.u = ((unsigned)u) << 16; return v.f;
}
__device__ __forceinline__ void bar() {
  asm volatile("" ::: "memory");
  __builtin_amdgcn_s_barrier();
  asm volatile("" ::: "memory");
}

// ---------------- fused fp32 -> bf16 convert (x + 4 weights) -----------------
__global__ __launch_bounds__(256) void cvt_all(
    const float* __restrict__ x,  const float* __restrict__ wq,
    const float* __restrict__ wk, const float* __restrict__ wv,
    const float* __restrict__ wo, u16* __restrict__ xb, u16* __restrict__ wb) {
  const int bid = blockIdx.x;
  const float* s;
  u16* d;
  int off;
  if (bid < 2048) {
    s = x; d = xb; off = bid * 2048;
  } else {
    const int w = bid - 2048;
    const int m = w >> 9;
    s = (m == 0) ? wq : ((m == 1) ? wk : ((m == 2) ? wv : wo));
    d = wb + ((size_t)m << 20);
    off = (w & 511) * 2048;
  }
  const int i = off + threadIdx.x * 8;
  const float4* s4 = (const float4*)(s + i);
  float4 a = s4[0], b = s4[1];
  u16x8 r;
  r[0] = f2bf(a.x); r[1] = f2bf(a.y); r[2] = f2bf(a.z); r[3] = f2bf(a.w);
  r[4] = f2bf(b.x); r[5] = f2bf(b.y); r[6] = f2bf(b.z); r[7] = f2bf(b.w);
  *(u16x8*)(d + i) = r;
}

// ---------------- QKV GEMM: 256x256, 8-phase, 16 MFMA/phase ------------------
// m201-geometry port of the proven gemm8 schedule. 8 waves (2M x 4N), BK=64.
// Stage ring (2 K-tiles/iter):
//  p0: Ah0(t2+1)  p1: Ah1(t2+1)  p2: Bq0,Bq1(t2+2)  p3: Bq2,Bq3(t2+2)+vmcnt(4)
//  p4: Ah0(t2+2)  p5: Ah1(t2+2)  p6: Bq0,Bq1(t2+3)  p7: Bq2,Bq3(t2+3)+vmcnt(4)
// vmcnt(4): after tile-t's last load exactly 4 newer loads issue -> publishes t.
// Epilogue scatters cols {Q,K,V} by col>>10 (row stride DIM).
__global__ __launch_bounds__(512, 2) void gemm8(
    const u16* __restrict__ A, const u16* __restrict__ B,
    u16* __restrict__ C, int nbm) {
  constexpr int NT = 16;
  __shared__ u16 As[2][256 * 64];
  __shared__ u16 Bs[2][256 * 64];

  const int tid = threadIdx.x;
  const int lane = tid & 63;
  const int wid = tid >> 6;
  const int wr = wid >> 2, wc = wid & 3;
  const int c15 = lane & 15, g = lane >> 4;
  const int lr = lane >> 3;
  const int lcs = ((lane & 7) ^ lr) << 3;

  const int cpx = gridDim.x >> 3;           // bijective XCD swizzle (192%8==0)
  const int bid = ((int)blockIdx.x & 7) * cpx + ((int)blockIdx.x >> 3);
  const int bm = bid % nbm;
  const int nb = bid / nbm;
  const u16* Ab = A + (size_t)bm * 256 * DIM;
  const u16* Bb = B + (size_t)nb * 256 * DIM;

  f32x4 acc[8][4];
#pragma unroll
  for (int m = 0; m < 8; ++m)
#pragma unroll
    for (int n = 0; n < 4; ++n) acc[m][n] = (f32x4){0.f, 0.f, 0.f, 0.f};

  auto stAh = [&](int buf, int half, int t) {   // one A half-tile: 2 loads/wave
    const int k0 = t * 64;
#pragma unroll
    for (int i = 0; i < 2; ++i) {
      const int c = half * 16 + wid * 2 + i;
      __builtin_amdgcn_global_load_lds(
          (const AS1 void*)(Ab + (size_t)(c * 8 + lr) * DIM + k0 + lcs),
          (AS3 void*)(&As[buf][c * 512]), 16, 0, 0);
    }
  };
  auto stBq = [&](int buf, int quarter, int t) { // one B quarter: 1 load/wave
    const int k0 = t * 64;
    const int c = quarter * 8 + wid;
    __builtin_amdgcn_global_load_lds(
        (const AS1 void*)(Bb + (size_t)(c * 8 + lr) * DIM + k0 + lcs),
        (AS3 void*)(&Bs[buf][c * 512]), 16, 0, 0);
  };

  // prologue: A(0), B(0), B(1); vmcnt(4) leaves only B(1) in flight.
  stAh(0, 0, 0); stAh(0, 1, 0);
  stBq(0, 0, 0); stBq(0, 1, 0); stBq(0, 2, 0); stBq(0, 3, 0);
  stBq(1, 0, 1); stBq(1, 1, 1); stBq(1, 2, 1); stBq(1, 3, 1);
  asm volatile("s_waitcnt vmcnt(4)" ::: "memory");
  bar();

  for (int t2 = 0; t2 < NT; t2 += 2) {
    bf16x8 bfrag[4][2];
#pragma unroll
    for (int p = 0; p < 8; ++p) {
      const int q = p & 3;
      const int buf = (p >> 2);            // tile t2 -> buf0, t2+1 -> buf1
      if (q == 0) {
#pragma unroll
        for (int n = 0; n < 4; ++n)
#pragma unroll
          for (int ks = 0; ks < 2; ++ks) {
            const int r = wc * 64 + n * 16 + c15;
            bfrag[n][ks] = *(const bf16x8*)(
                &Bs[buf][r * 64 + ((ks * 32 + g * 8) ^ ((r & 7) << 3))]);
          }
      }
      bf16x8 af[2][2];
#pragma unroll
      for (int m = 0; m < 2; ++m)
#pragma unroll
        for (int ks = 0; ks < 2; ++ks) {
          const int r = wr * 128 + (q * 2 + m) * 16 + c15;
          af[m][ks] = *(const bf16x8*)(
              &As[buf][r * 64 + ((ks * 32 + g * 8) ^ ((r & 7) << 3))]);
        }
      // ---- stage slot for this phase ----
      const bool s2 = (t2 + 2) < NT;
      const bool s3 = (t2 + 3) < NT;
      if (p == 0) {
        stAh(1, 0, t2 + 1);
      } else if (p == 1) {
        stAh(1, 1, t2 + 1);
      } else if (p == 2) {
        if (s2) { stBq(0, 0, t2 + 2); stBq(0, 1, t2 + 2); }
      } else if (p == 3) {
        if (s2) { stBq(0, 2, t2 + 2); stBq(0, 3, t2 + 2);
                  asm volatile("s_waitcnt vmcnt(4)" ::: "memory"); }
        else    { asm volatile("s_waitcnt vmcnt(0)" ::: "memory"); }
      } else if (p == 4) {
        if (s2) stAh(0, 0, t2 + 2);
      } else if (p == 5) {
        if (s2) stAh(0, 1, t2 + 2);
      } else if (p == 6) {
        if (s3) { stBq(1, 0, t2 + 3); stBq(1, 1, t2 + 3); }
      } else {
        if (s3) { stBq(1, 2, t2 + 3); stBq(1, 3, t2 + 3);
                  asm volatile("s_waitcnt vmcnt(4)" ::: "memory"); }
        else if (s2) { asm volatile("s_waitcnt vmcnt(0)" ::: "memory"); }
      }
      bar();
      __builtin_amdgcn_s_setprio(1);
#pragma unroll
      for (int m = 0; m < 2; ++m)
#pragma unroll
        for (int n = 0; n < 4; ++n)
#pragma unroll
          for (int ks = 0; ks < 2; ++ks)
            acc[q * 2 + m][n] = __builtin_amdgcn_mfma_f32_16x16x32_bf16(
                af[m][ks], bfrag[n][ks], acc[q * 2 + m][n], 0, 0, 0);
      __builtin_amdgcn_s_setprio(0);
      bar();
    }
  }

  // epilogue: C/D layout col=lane&15, row=(lane>>4)*4+j; split cols to Q/K/V
#pragma unroll
  for (int m = 0; m < 8; ++m) {
    const int row0 = bm * 256 + wr * 128 + m * 16 + g * 4;
#pragma unroll
    for (int n = 0; n < 4; ++n) {
      const int col = nb * 256 + wc * 64 + n * 16 + c15;
#pragma unroll
      for (int j = 0; j < 4; ++j) {
        u16* dst = C + (size_t)(col >> 10) * (size_t)XN_EL +
                   (col & 1023) + (size_t)(row0 + j) * DIM;
        *dst = f2bf(acc[m][n][j]);
      }
    }
  }
}

// ---------------- out-proj GEMM (4-phase, R11 exact) -------------------------
template <int BM, int BN, int WM, int WN, int OS, typename OUT_T>
__global__ __launch_bounds__(WM * WN * 64, 2) void gemm3(
    const u16* __restrict__ A, const u16* __restrict__ B,
    OUT_T* __restrict__ C, int nbm) {
  constexpr int NW = WM * WN;
  constexpr int RM = BM / WM, RN = BN / WN;
  constexpr int MF = RM / 16, NF = RN / 16;
  constexpr int MPH = MF / 4;
  constexpr int NT = DIM / 64;
  constexpr int CA = BM / 8, CB = BN / 8;
  constexpr int ANW = CA / NW;
  constexpr int BNW = CB / NW;

  __shared__ u16 As[2][BM * 64];
  __shared__ u16 Bs[2][BN * 64];

  const int tid = threadIdx.x;
  const int lane = tid & 63;
  const int wid = tid >> 6;
  const int wr = wid / WN, wc = wid % WN;
  const int c15 = lane & 15, g = lane >> 4;
  const int lr = lane >> 3;
  const int lcs = ((lane & 7) ^ lr) << 3;

  const int cpx = gridDim.x >> 3;
  const int bid = ((int)blockIdx.x & 7) * cpx + ((int)blockIdx.x >> 3);
  const int bm = bid % nbm;
  const int nb = bid / nbm;
  const u16* Ab = A + (size_t)bm * BM * DIM;
  const u16* Bb = B + (size_t)nb * BN * DIM;

  f32x4 acc[MF][NF];
#pragma unroll
  for (int m = 0; m < MF; ++m)
#pragma unroll
    for (int n = 0; n < NF; ++n) acc[m][n] = (f32x4){0.f, 0.f, 0.f, 0.f};

  auto stA = [&](int buf, int half, int k0) {
#pragma unroll
    for (int i = 0; i < ANW / 2; ++i) {
      const int c = half * (CA / 2) + wid * (ANW / 2) + i;
      __builtin_amdgcn_global_load_lds(
          (const AS1 void*)(Ab + (size_t)(c * 8 + lr) * DIM + k0 + lcs),
          (AS3 void*)(&As[buf][c * 512]), 16, 0, 0);
    }
  };
  auto stB = [&](int buf, int k0) {
#pragma unroll
    for (int i = 0; i < BNW; ++i) {
      const int c = wid * BNW + i;
      __builtin_amdgcn_global_load_lds(
          (const AS1 void*)(Bb + (size_t)(c * 8 + lr) * DIM + k0 + lcs),
          (AS3 void*)(&Bs[buf][c * 512]), 16, 0, 0);
    }
  };

  stA(0, 0, 0); stA(0, 1, 0);
  stB(0, 0); stB(1, 64);
  asm volatile("s_waitcnt vmcnt(4)" ::: "memory");
  bar();

  for (int t = 0; t < NT; ++t) {
    const int buf = t & 1;
    const int k0 = t * 64;
    bf16x8 bfrag[NF][2];
#pragma unroll
    for (int p = 0; p < 4; ++p) {
      if (p == 0) {
#pragma unroll
        for (int n = 0; n < NF; ++n)
#pragma unroll
          for (int ks = 0; ks < 2; ++ks) {
            const int r = wc * RN + n * 16 + c15;
            bfrag[n][ks] = *(const bf16x8*)(
                &Bs[buf][r * 64 + ((ks * 32 + g * 8) ^ ((r & 7) << 3))]);
          }
      }
      bf16x8 af[MPH][2];
#pragma unroll
      for (int m = 0; m < MPH; ++m)
#pragma unroll
        for (int ks = 0; ks < 2; ++ks) {
          const int r = wr * RM + (p * MPH + m) * 16 + c15;
          af[m][ks] = *(const bf16x8*)(
              &As[buf][r * 64 + ((ks * 32 + g * 8) ^ ((r & 7) << 3))]);
        }
      if (p == 0) {
        if (t + 1 < NT) stA(buf ^ 1, 0, k0 + 64);
      } else if (p == 1) {
        if (t + 1 < NT) stA(buf ^ 1, 1, k0 + 64);
      } else if (p == 2) {
        if (t + 2 < NT) stB(buf, k0 + 128);
      } else {
        if (t < NT - 2) asm volatile("s_waitcnt vmcnt(4)" ::: "memory");
        else            asm volatile("s_waitcnt vmcnt(0)" ::: "memory");
      }
      bar();
      __builtin_amdgcn_s_setprio(1);
#pragma unroll
      for (int m = 0; m < MPH; ++m)
#pragma unroll
        for (int n = 0; n < NF; ++n)
#pragma unroll
          for (int ks = 0; ks < 2; ++ks)
            acc[p * MPH + m][n] = __builtin_amdgcn_mfma_f32_16x16x32_bf16(
                af[m][ks], bfrag[n][ks], acc[p * MPH + m][n], 0, 0, 0);
      __builtin_amdgcn_s_setprio(0);
      bar();
    }
  }

#pragma unroll
  for (int m = 0; m < MF; ++m) {
    const int row0 = bm * BM + wr * RM + m * 16 + g * 4;
#pragma unroll
    for (int n = 0; n < NF; ++n) {
      const int col = nb * BN + wc * RN + n * 16 + c15;
#pragma unroll
      for (int j = 0; j < 4; ++j) {
        const size_t idx = (size_t)(row0 + j) * OS + col;
        if constexpr (sizeof(OUT_T) == 2) C[idx] = f2bf(acc[m][n][j]);
        else C[idx] = acc[m][n][j];
      }
    }
  }
}

// ---------------- sparse flash attention (R16 exact: pair-locked grid) -------
__global__ __launch_bounds__(256) void sparse_attn(
    const u16* __restrict__ Q, const u16* __restrict__ K,
    const u16* __restrict__ V, u16* __restrict__ AO) {
  __shared__ u16 Ks[64 * 72];
  __shared__ u16 Vt[64 * 72];
  __shared__ u16 Pl[4][16 * 72];
  __shared__ float Pg[4][16];

  const int tid = threadIdx.x;
  const int lane = tid & 63;
  const int wid = tid >> 6;

  const int id = blockIdx.x;
  const int xcd = id & 7;
  const int slot = id >> 3;        // 0..131
  const int pl = slot / 33;        // 0..3
  const int within = slot % 33;    // 0: global row; 1..32: q-chunks
  const int pair = xcd * 4 + pl;   // 0..31
  const int by = pair & 15;
  const int bz = pair >> 4;

  const size_t ha = (size_t)bz * T_SEQ * DIM + (size_t)by * HDIM;
  const u16* Qp = Q + ha;
  const u16* Kp = K + ha;
  const u16* Vp = V + ha;

  if (within == 0) {
    float* qs   = (float*)Pg;
    float* ps   = (float*)Ks;
    float* rbuf = (float*)Vt;
    float* red  = (float*)(&Pl[0][0]);

    if (tid < HDIM) qs[tid] = bf2f(Qp[tid]);
    __syncthreads();

    float lsum = 0.f;
#pragma unroll
    for (int j = 0; j < 8; ++j) {
      const int k = tid + 256 * j;
      const u16* kr = Kp + (size_t)k * DIM;
      float acc = 0.f;
#pragma unroll
      for (int d0 = 0; d0 < 8; ++d0) {
        u16x8 kv = *(const u16x8*)(kr + d0 * 8);
#pragma unroll
        for (int e = 0; e < 8; ++e) acc += qs[d0 * 8 + e] * bf2f(kv[e]);
      }
      const float p = __expf(acc * 0.125f);
      ps[k] = p;
      lsum += p;
    }
#pragma unroll
    for (int s = 1; s < 64; s <<= 1) lsum += __shfl_xor(lsum, s);
    if (lane == 0) red[wid] = lsum;
    __syncthreads();
    const float denom = red[0] + red[1] + red[2] + red[3];

    const int kg = tid >> 3, dg = tid & 7;
    float facc[8] = {0.f, 0.f, 0.f, 0.f, 0.f, 0.f, 0.f, 0.f};
#pragma unroll 8
    for (int i = 0; i < 64; ++i) {
      const int k = kg * 64 + i;
      const u16x8 vv = *(const u16x8*)(Vp + (size_t)k * DIM + dg * 8);
      const float p = ps[k];
#pragma unroll
      for (int e = 0; e < 8; ++e) facc[e] += p * bf2f(vv[e]);
    }
#pragma unroll
    for (int e = 0; e < 8; ++e) rbuf[kg * 64 + dg * 8 + e] = facc[e];
    __syncthreads();
    if (tid < HDIM) {
      float tot = 0.f;
#pragma unroll
      for (int k2 = 0; k2 < 32; ++k2) tot += rbuf[k2 * 64 + tid];
      AO[ha + tid] = f2bf(tot / denom);
    }
    return;
  }

  const int c15 = lane & 15;
  const int g = lane >> 4;
  const int q0 = (within - 1) * 64;
  const int r0 = q0 + wid * 16;

  bf16x8 qf0, qf1;
  {
    const u16* qp = Qp + (size_t)(r0 + c15) * DIM + g * 8;
    qf0 = *(const bf16x8*)qp;
    qf1 = *(const bf16x8*)(qp + 32);
  }

  float lrun[4] = {0.f, 0.f, 0.f, 0.f};
  f32x4 ao[4];
#pragma unroll
  for (int c = 0; c < 4; ++c) ao[c] = (f32x4){0.f, 0.f, 0.f, 0.f};

  const int klo = (q0 > WIN) ? (q0 - WIN) : 0;
  int khi = q0 + 64 + WIN;
  if (khi > T_SEQ) khi = T_SEQ;
  const int nt = (khi - klo) >> 6;

  const int srr = tid >> 2;
  const int scc = (tid & 3) * 16;
  const int vr = srr ^ (scc & 48);

  const u16* kbase = Kp + (size_t)(klo + srr) * DIM + scc;
  const u16* vbase = Vp + (size_t)(klo + srr) * DIM + scc;
  u16x8 kp0 = *(const u16x8*)kbase;
  u16x8 kp1 = *(const u16x8*)(kbase + 8);
  u16x8 vp0 = *(const u16x8*)vbase;
  u16x8 vp1 = *(const u16x8*)(vbase + 8);

  for (int ti = 0; ti < nt; ++ti) {
    const int kt = klo + ti * 64;
    *(u16x8*)(Ks + srr * 72 + scc) = kp0;
    *(u16x8*)(Ks + srr * 72 + scc + 8) = kp1;
#pragma unroll
    for (int e = 0; e < 8; ++e) {
      Vt[(scc + e) * 72 + vr] = vp0[e];
      Vt[(scc + 8 + e) * 72 + vr] = vp1[e];
    }
    __syncthreads();

    if (ti + 1 < nt) {
      const u16* kn = kbase + (size_t)(ti + 1) * 64 * DIM;
      const u16* vn = vbase + (size_t)(ti + 1) * 64 * DIM;
      kp0 = *(const u16x8*)kn;
      kp1 = *(const u16x8*)(kn + 8);
      vp0 = *(const u16x8*)vn;
      vp1 = *(const u16x8*)(vn + 8);
    }

    f32x4 s[4];
#pragma unroll
    for (int t = 0; t < 4; ++t) {
      const u16* kr = Ks + (t * 16 + c15) * 72 + g * 8;
      bf16x8 ka = *(const bf16x8*)kr;
      bf16x8 kb = *(const bf16x8*)(kr + 32);
      f32x4 z = (f32x4){0.f, 0.f, 0.f, 0.f};
      z = __builtin_amdgcn_mfma_f32_16x16x32_bf16(qf0, ka, z, 0, 0, 0);
      s[t] = __builtin_amdgcn_mfma_f32_16x16x32_bf16(qf1, kb, z, 0, 0, 0);
    }
    if (kt >= r0 - 113 && kt <= r0 + 65) {
#pragma unroll
      for (int j = 0; j < 4; ++j) {
#pragma unroll
        for (int t = 0; t < 4; ++t) {
          const float p = __expf(s[t][j] * 0.125f);
          lrun[j] += p;
          Pl[wid][(g * 4 + j) * 72 + t * 16 + c15] = f2bf(p);
        }
      }
    } else {
#pragma unroll
      for (int j = 0; j < 4; ++j) {
        const int qg = r0 + g * 4 + j;
#pragma unroll
        for (int t = 0; t < 4; ++t) {
          const int kg = kt + t * 16 + c15;
          const int dd = qg - kg;
          const bool ok = (kg == 0) || (dd <= WIN && dd >= -WIN);
          const float p = ok ? __expf(s[t][j] * 0.125f) : 0.f;
          lrun[j] += p;
          Pl[wid][(g * 4 + j) * 72 + t * 16 + c15] = f2bf(p);
        }
      }
    }
    asm volatile("s_waitcnt lgkmcnt(0)" ::: "memory");

    const bf16x8 pa0 = *(const bf16x8*)(&Pl[wid][c15 * 72 + g * 8]);
    const bf16x8 pa1 = *(const bf16x8*)(&Pl[wid][c15 * 72 + 32 + g * 8]);
#pragma unroll
    for (int c = 0; c < 4; ++c) {
      const int rb = (c * 16 + c15) * 72;
      bf16x8 va = *(const bf16x8*)(Vt + rb + ((g * 8) ^ (c << 4)));
      bf16x8 vb = *(const bf16x8*)(Vt + rb + ((32 + g * 8) ^ (c << 4)));
      ao[c] = __builtin_amdgcn_mfma_f32_16x16x32_bf16(pa0, va, ao[c], 0, 0, 0);
      ao[c] = __builtin_amdgcn_mfma_f32_16x16x32_bf16(pa1, vb, ao[c], 0, 0, 0);
    }
    __syncthreads();
  }

  float ltot[4];
#pragma unroll
  for (int j = 0; j < 4; ++j) {
    float ls = lrun[j];
    ls += __shfl_xor(ls, 1);
    ls += __shfl_xor(ls, 2);
    ls += __shfl_xor(ls, 4);
    ls += __shfl_xor(ls, 8);
    ltot[j] = ls;
  }

  if (klo > 0) {
    const u16x8 qu0 = *(const u16x8*)&qf0;
    const u16x8 qu1 = *(const u16x8*)&qf1;
    const u16x8 k0a = *(const u16x8*)(Kp + g * 8);
    const u16x8 k0b = *(const u16x8*)(Kp + 32 + g * 8);
    float sg = 0.f;
#pragma unroll
    for (int e = 0; e < 8; ++e)
      sg += bf2f(qu0[e]) * bf2f(k0a[e]) + bf2f(qu1[e]) * bf2f(k0b[e]);
    sg += __shfl_xor(sg, 16);
    sg += __shfl_xor(sg, 32);
    const float pg = __expf(sg * 0.125f);
    Pg[wid][c15] = pg;
    asm volatile("s_waitcnt lgkmcnt(0)" ::: "memory");
#pragma unroll
    for (int j = 0; j < 4; ++j) {
      const float pj = Pg[wid][g * 4 + j];
      ltot[j] += pj;
#pragma unroll
      for (int c = 0; c < 4; ++c)
        ao[c][j] += pj * bf2f(Vp[c * 16 + c15]);
    }
  }

#pragma unroll
  for (int j = 0; j < 4; ++j) {
    const int qrow = r0 + g * 4 + j;
    if (qrow == 0) continue;
    const float inv = 1.0f / ltot[j];
#pragma unroll
    for (int c = 0; c < 4; ++c)
      AO[ha + (size_t)qrow * DIM + c * 16 + c15] = f2bf(ao[c][j] * inv);
  }
}

// ---------------- launch -----------------------------------------------------
extern "C" void kernel_launch(void* const* d_in, const int* in_sizes, int n_in,
                              void* d_out, int out_size, void* d_ws, size_t ws_size,
                              hipStream_t stream) {
  const float* x  = (const float*)d_in[0];
  const float* Wq = (const float*)d_in[1];
  const float* Wk = (const float*)d_in[2];
  const float* Wv = (const float*)d_in[3];
  const float* Wo = (const float*)d_in[4];
  float* out = (float*)d_out;

  const int WN = DIM * DIM;

  u16* ws  = (u16*)d_ws;
  u16* xb  = ws;                      // bf16 x [4096,1024]; reused as AO
  u16* wb  = ws + (size_t)XN_EL;      // Wq,Wk,Wv,Wo bf16 contiguous
  u16* Wob = wb + (size_t)3 * WN;
  u16* Qb  = wb + (size_t)4 * WN;     // [4096,1024]
  u16* Kb  = Qb + (size_t)XN_EL;      // [4096,1024]
  u16* Vb  = Kb + (size_t)XN_EL;      // [4096,1024]

  cvt_all<<<4096, 256, 0, stream>>>(x, Wq, Wk, Wv, Wo, xb, wb);

  // fused QKV: 256x256 tiles, 16 MFMA/phase, grid 16*12 = 192
  gemm8<<<192, 512, 0, stream>>>(xb, wb, Qb, 16);

  // attention: pair-locked 1-D grid (8 XCDs x 4 heads x 33 blocks)
  sparse_attn<<<1056, 256, 0, stream>>>(Qb, Kb, Vb, xb);

  // output projection: 128x128 tiles, grid 256
  gemm3<128, 128, 2, 2, DIM, float><<<256, 256, 0, stream>>>(xb, Wob, out, 32);
}

// Round 18
// 98.794 us; speedup vs baseline: 1.0506x; 1.0506x over previous
//
#include <hip/hip_runtime.h>

typedef unsigned short u16;
typedef __attribute__((ext_vector_type(8))) __bf16 bf16x8;
typedef __attribute__((ext_vector_type(4))) float f32x4;
typedef __attribute__((ext_vector_type(8))) u16 u16x8;

#define T_SEQ 2048
#define DIM   1024
#define HDIM  64
#define WIN   128
#define XN_EL (2 * T_SEQ * DIM)   // 4194304

#define AS1 __attribute__((address_space(1)))
#define AS3 __attribute__((address_space(3)))

__device__ __forceinline__ u16 f2bf(float f) {
  union { float f; unsigned u; } v; v.f = f;
  unsigned r = v.u + 0x7fffu + ((v.u >> 16) & 1u);  // RNE
  return (u16)(r >> 16);
}
__device__ __forceinline__ float bf2f(u16 u) {
  union { unsigned u; float f; } v; v.u = ((unsigned)u) << 16; return v.f;
}
__device__ __forceinline__ void bar() {
  asm volatile("" ::: "memory");
  __builtin_amdgcn_s_barrier();
  asm volatile("" ::: "memory");
}

// ---------------- fused fp32 -> bf16 convert (x + 4 weights) -----------------
__global__ __launch_bounds__(256) void cvt_all(
    const float* __restrict__ x,  const float* __restrict__ wq,
    const float* __restrict__ wk, const float* __restrict__ wv,
    const float* __restrict__ wo, u16* __restrict__ xb, u16* __restrict__ wb) {
  const int bid = blockIdx.x;
  const float* s;
  u16* d;
  int off;
  if (bid < 2048) {
    s = x; d = xb; off = bid * 2048;
  } else {
    const int w = bid - 2048;
    const int m = w >> 9;
    s = (m == 0) ? wq : ((m == 1) ? wk : ((m == 2) ? wv : wo));
    d = wb + ((size_t)m << 20);
    off = (w & 511) * 2048;
  }
  const int i = off + threadIdx.x * 8;
  const float4* s4 = (const float4*)(s + i);
  float4 a = s4[0], b = s4[1];
  u16x8 r;
  r[0] = f2bf(a.x); r[1] = f2bf(a.y); r[2] = f2bf(a.z); r[3] = f2bf(a.w);
  r[4] = f2bf(b.x); r[5] = f2bf(b.y); r[6] = f2bf(b.z); r[7] = f2bf(b.w);
  *(u16x8*)(d + i) = r;
}

// ---------------- QKV GEMM: 256x192, 8-phase / 2 K-tiles per iter (R16) ------
__global__ __launch_bounds__(512, 2) void gemm8(
    const u16* __restrict__ A, const u16* __restrict__ B,
    u16* __restrict__ C, int nbm) {
  constexpr int NT = 16;
  __shared__ u16 As[2][256 * 64];
  __shared__ u16 Bs[2][192 * 64];

  const int tid = threadIdx.x;
  const int lane = tid & 63;
  const int wid = tid >> 6;
  const int wr = wid >> 2, wc = wid & 3;
  const int c15 = lane & 15, g = lane >> 4;
  const int lr = lane >> 3;
  const int lcs = ((lane & 7) ^ lr) << 3;

  const int cpx = gridDim.x >> 3;
  const int bid = ((int)blockIdx.x & 7) * cpx + ((int)blockIdx.x >> 3);
  const int bm = bid % nbm;
  const int nb = bid / nbm;
  const u16* Ab = A + (size_t)bm * 256 * DIM;
  const u16* Bb = B + (size_t)nb * 192 * DIM;

  f32x4 acc[8][3];
#pragma unroll
  for (int m = 0; m < 8; ++m)
#pragma unroll
    for (int n = 0; n < 3; ++n) acc[m][n] = (f32x4){0.f, 0.f, 0.f, 0.f};

  auto stAh = [&](int buf, int half, int t) {
    const int k0 = t * 64;
#pragma unroll
    for (int i = 0; i < 2; ++i) {
      const int c = half * 16 + wid * 2 + i;
      __builtin_amdgcn_global_load_lds(
          (const AS1 void*)(Ab + (size_t)(c * 8 + lr) * DIM + k0 + lcs),
          (AS3 void*)(&As[buf][c * 512]), 16, 0, 0);
    }
  };
  auto stBt = [&](int buf, int third, int t) {
    const int k0 = t * 64;
    const int c = third * 8 + wid;
    __builtin_amdgcn_global_load_lds(
        (const AS1 void*)(Bb + (size_t)(c * 8 + lr) * DIM + k0 + lcs),
        (AS3 void*)(&Bs[buf][c * 512]), 16, 0, 0);
  };

  stAh(0, 0, 0); stAh(0, 1, 0);
  stBt(0, 0, 0); stBt(0, 1, 0); stBt(0, 2, 0);
  stBt(1, 0, 1); stBt(1, 1, 1); stBt(1, 2, 1);
  asm volatile("s_waitcnt vmcnt(3)" ::: "memory");
  bar();

  for (int t2 = 0; t2 < NT; t2 += 2) {
    bf16x8 bfrag[3][2];
#pragma unroll
    for (int p = 0; p < 8; ++p) {
      const int q = p & 3;
      const int buf = (p >> 2);
      if (q == 0) {
#pragma unroll
        for (int n = 0; n < 3; ++n)
#pragma unroll
          for (int ks = 0; ks < 2; ++ks) {
            const int r = wc * 48 + n * 16 + c15;
            bfrag[n][ks] = *(const bf16x8*)(
                &Bs[buf][r * 64 + ((ks * 32 + g * 8) ^ ((r & 7) << 3))]);
          }
      }
      bf16x8 af[2][2];
#pragma unroll
      for (int m = 0; m < 2; ++m)
#pragma unroll
        for (int ks = 0; ks < 2; ++ks) {
          const int r = wr * 128 + (q * 2 + m) * 16 + c15;
          af[m][ks] = *(const bf16x8*)(
              &As[buf][r * 64 + ((ks * 32 + g * 8) ^ ((r & 7) << 3))]);
        }
      const bool s2 = (t2 + 2) < NT;
      const bool s3 = (t2 + 3) < NT;
      if (p == 0) {
        stAh(1, 0, t2 + 1);
      } else if (p == 1) {
        stAh(1, 1, t2 + 1);
        if (s2) stBt(0, 0, t2 + 2);
      } else if (p == 2) {
        if (s2) stBt(0, 1, t2 + 2);
      } else if (p == 3) {
        if (s2) { stBt(0, 2, t2 + 2);
                  asm volatile("s_waitcnt vmcnt(3)" ::: "memory"); }
        else    { asm volatile("s_waitcnt vmcnt(0)" ::: "memory"); }
      } else if (p == 4) {
        if (s2) stAh(0, 0, t2 + 2);
      } else if (p == 5) {
        if (s2) stAh(0, 1, t2 + 2);
        if (s3) stBt(1, 0, t2 + 3);
      } else if (p == 6) {
        if (s3) stBt(1, 1, t2 + 3);
      } else {
        if (s3) { stBt(1, 2, t2 + 3);
                  asm volatile("s_waitcnt vmcnt(3)" ::: "memory"); }
        else if (s2) { asm volatile("s_waitcnt vmcnt(0)" ::: "memory"); }
      }
      bar();
      __builtin_amdgcn_s_setprio(1);
#pragma unroll
      for (int m = 0; m < 2; ++m)
#pragma unroll
        for (int n = 0; n < 3; ++n)
#pragma unroll
          for (int ks = 0; ks < 2; ++ks)
            acc[q * 2 + m][n] = __builtin_amdgcn_mfma_f32_16x16x32_bf16(
                af[m][ks], bfrag[n][ks], acc[q * 2 + m][n], 0, 0, 0);
      __builtin_amdgcn_s_setprio(0);
      bar();
    }
  }

#pragma unroll
  for (int m = 0; m < 8; ++m) {
    const int row0 = bm * 256 + wr * 128 + m * 16 + g * 4;
#pragma unroll
    for (int n = 0; n < 3; ++n) {
      const int col = nb * 192 + wc * 48 + n * 16 + c15;
#pragma unroll
      for (int j = 0; j < 4; ++j) {
        u16* dst = C + (size_t)(col >> 10) * (size_t)XN_EL +
                   (col & 1023) + (size_t)(row0 + j) * DIM;
        *dst = f2bf(acc[m][n][j]);
      }
    }
  }
}

// ---------------- out-proj GEMM (4-phase, R11 exact) -------------------------
template <int BM, int BN, int WM, int WN, int OS, typename OUT_T>
__global__ __launch_bounds__(WM * WN * 64, 2) void gemm3(
    const u16* __restrict__ A, const u16* __restrict__ B,
    OUT_T* __restrict__ C, int nbm) {
  constexpr int NW = WM * WN;
  constexpr int RM = BM / WM, RN = BN / WN;
  constexpr int MF = RM / 16, NF = RN / 16;
  constexpr int MPH = MF / 4;
  constexpr int NT = DIM / 64;
  constexpr int CA = BM / 8, CB = BN / 8;
  constexpr int ANW = CA / NW;
  constexpr int BNW = CB / NW;

  __shared__ u16 As[2][BM * 64];
  __shared__ u16 Bs[2][BN * 64];

  const int tid = threadIdx.x;
  const int lane = tid & 63;
  const int wid = tid >> 6;
  const int wr = wid / WN, wc = wid % WN;
  const int c15 = lane & 15, g = lane >> 4;
  const int lr = lane >> 3;
  const int lcs = ((lane & 7) ^ lr) << 3;

  const int cpx = gridDim.x >> 3;
  const int bid = ((int)blockIdx.x & 7) * cpx + ((int)blockIdx.x >> 3);
  const int bm = bid % nbm;
  const int nb = bid / nbm;
  const u16* Ab = A + (size_t)bm * BM * DIM;
  const u16* Bb = B + (size_t)nb * BN * DIM;

  f32x4 acc[MF][NF];
#pragma unroll
  for (int m = 0; m < MF; ++m)
#pragma unroll
    for (int n = 0; n < NF; ++n) acc[m][n] = (f32x4){0.f, 0.f, 0.f, 0.f};

  auto stA = [&](int buf, int half, int k0) {
#pragma unroll
    for (int i = 0; i < ANW / 2; ++i) {
      const int c = half * (CA / 2) + wid * (ANW / 2) + i;
      __builtin_amdgcn_global_load_lds(
          (const AS1 void*)(Ab + (size_t)(c * 8 + lr) * DIM + k0 + lcs),
          (AS3 void*)(&As[buf][c * 512]), 16, 0, 0);
    }
  };
  auto stB = [&](int buf, int k0) {
#pragma unroll
    for (int i = 0; i < BNW; ++i) {
      const int c = wid * BNW + i;
      __builtin_amdgcn_global_load_lds(
          (const AS1 void*)(Bb + (size_t)(c * 8 + lr) * DIM + k0 + lcs),
          (AS3 void*)(&Bs[buf][c * 512]), 16, 0, 0);
    }
  };

  stA(0, 0, 0); stA(0, 1, 0);
  stB(0, 0); stB(1, 64);
  asm volatile("s_waitcnt vmcnt(4)" ::: "memory");
  bar();

  for (int t = 0; t < NT; ++t) {
    const int buf = t & 1;
    const int k0 = t * 64;
    bf16x8 bfrag[NF][2];
#pragma unroll
    for (int p = 0; p < 4; ++p) {
      if (p == 0) {
#pragma unroll
        for (int n = 0; n < NF; ++n)
#pragma unroll
          for (int ks = 0; ks < 2; ++ks) {
            const int r = wc * RN + n * 16 + c15;
            bfrag[n][ks] = *(const bf16x8*)(
                &Bs[buf][r * 64 + ((ks * 32 + g * 8) ^ ((r & 7) << 3))]);
          }
      }
      bf16x8 af[MPH][2];
#pragma unroll
      for (int m = 0; m < MPH; ++m)
#pragma unroll
        for (int ks = 0; ks < 2; ++ks) {
          const int r = wr * RM + (p * MPH + m) * 16 + c15;
          af[m][ks] = *(const bf16x8*)(
              &As[buf][r * 64 + ((ks * 32 + g * 8) ^ ((r & 7) << 3))]);
        }
      if (p == 0) {
        if (t + 1 < NT) stA(buf ^ 1, 0, k0 + 64);
      } else if (p == 1) {
        if (t + 1 < NT) stA(buf ^ 1, 1, k0 + 64);
      } else if (p == 2) {
        if (t + 2 < NT) stB(buf, k0 + 128);
      } else {
        if (t < NT - 2) asm volatile("s_waitcnt vmcnt(4)" ::: "memory");
        else            asm volatile("s_waitcnt vmcnt(0)" ::: "memory");
      }
      bar();
      __builtin_amdgcn_s_setprio(1);
#pragma unroll
      for (int m = 0; m < MPH; ++m)
#pragma unroll
        for (int n = 0; n < NF; ++n)
#pragma unroll
          for (int ks = 0; ks < 2; ++ks)
            acc[p * MPH + m][n] = __builtin_amdgcn_mfma_f32_16x16x32_bf16(
                af[m][ks], bfrag[n][ks], acc[p * MPH + m][n], 0, 0, 0);
      __builtin_amdgcn_s_setprio(0);
      bar();
    }
  }

#pragma unroll
  for (int m = 0; m < MF; ++m) {
    const int row0 = bm * BM + wr * RM + m * 16 + g * 4;
#pragma unroll
    for (int n = 0; n < NF; ++n) {
      const int col = nb * BN + wc * RN + n * 16 + c15;
#pragma unroll
      for (int j = 0; j < 4; ++j) {
        const size_t idx = (size_t)(row0 + j) * OS + col;
        if constexpr (sizeof(OUT_T) == 2) C[idx] = f2bf(acc[m][n][j]);
        else C[idx] = acc[m][n][j];
      }
    }
  }
}

// ---------------- sparse flash attention (pair-locked grid, R16 exact) -------
__global__ __launch_bounds__(256) void sparse_attn(
    const u16* __restrict__ Q, const u16* __restrict__ K,
    const u16* __restrict__ V, u16* __restrict__ AO) {
  __shared__ u16 Ks[64 * 72];
  __shared__ u16 Vt[64 * 72];
  __shared__ u16 Pl[4][16 * 72];
  __shared__ float Pg[4][16];

  const int tid = threadIdx.x;
  const int lane = tid & 63;
  const int wid = tid >> 6;

  const int id = blockIdx.x;
  const int xcd = id & 7;
  const int slot = id >> 3;        // 0..131
  const int pl = slot / 33;        // 0..3
  const int within = slot % 33;    // 0: global row; 1..32: q-chunks
  const int pair = xcd * 4 + pl;   // 0..31
  const int by = pair & 15;
  const int bz = pair >> 4;

  const size_t ha = (size_t)bz * T_SEQ * DIM + (size_t)by * HDIM;
  const u16* Qp = Q + ha;
  const u16* Kp = K + ha;
  const u16* Vp = V + ha;

  if (within == 0) {
    float* qs   = (float*)Pg;
    float* ps   = (float*)Ks;
    float* rbuf = (float*)Vt;
    float* red  = (float*)(&Pl[0][0]);

    if (tid < HDIM) qs[tid] = bf2f(Qp[tid]);
    __syncthreads();

    float lsum = 0.f;
#pragma unroll
    for (int j = 0; j < 8; ++j) {
      const int k = tid + 256 * j;
      const u16* kr = Kp + (size_t)k * DIM;
      float acc = 0.f;
#pragma unroll
      for (int d0 = 0; d0 < 8; ++d0) {
        u16x8 kv = *(const u16x8*)(kr + d0 * 8);
#pragma unroll
        for (int e = 0; e < 8; ++e) acc += qs[d0 * 8 + e] * bf2f(kv[e]);
      }
      const float p = __expf(acc * 0.125f);
      ps[k] = p;
      lsum += p;
    }
#pragma unroll
    for (int s = 1; s < 64; s <<= 1) lsum += __shfl_xor(lsum, s);
    if (lane == 0) red[wid] = lsum;
    __syncthreads();
    const float denom = red[0] + red[1] + red[2] + red[3];

    const int kg = tid >> 3, dg = tid & 7;
    float facc[8] = {0.f, 0.f, 0.f, 0.f, 0.f, 0.f, 0.f, 0.f};
#pragma unroll 8
    for (int i = 0; i < 64; ++i) {
      const int k = kg * 64 + i;
      const u16x8 vv = *(const u16x8*)(Vp + (size_t)k * DIM + dg * 8);
      const float p = ps[k];
#pragma unroll
      for (int e = 0; e < 8; ++e) facc[e] += p * bf2f(vv[e]);
    }
#pragma unroll
    for (int e = 0; e < 8; ++e) rbuf[kg * 64 + dg * 8 + e] = facc[e];
    __syncthreads();
    if (tid < HDIM) {
      float tot = 0.f;
#pragma unroll
      for (int k2 = 0; k2 < 32; ++k2) tot += rbuf[k2 * 64 + tid];
      AO[ha + tid] = f2bf(tot / denom);
    }
    return;
  }

  const int c15 = lane & 15;
  const int g = lane >> 4;
  const int q0 = (within - 1) * 64;
  const int r0 = q0 + wid * 16;

  bf16x8 qf0, qf1;
  {
    const u16* qp = Qp + (size_t)(r0 + c15) * DIM + g * 8;
    qf0 = *(const bf16x8*)qp;
    qf1 = *(const bf16x8*)(qp + 32);
  }

  float lrun[4] = {0.f, 0.f, 0.f, 0.f};
  f32x4 ao[4];
#pragma unroll
  for (int c = 0; c < 4; ++c) ao[c] = (f32x4){0.f, 0.f, 0.f, 0.f};

  const int klo = (q0 > WIN) ? (q0 - WIN) : 0;
  int khi = q0 + 64 + WIN;
  if (khi > T_SEQ) khi = T_SEQ;
  const int nt = (khi - klo) >> 6;

  const int srr = tid >> 2;
  const int scc = (tid & 3) * 16;
  const int vr = srr ^ (scc & 48);

  const u16* kbase = Kp + (size_t)(klo + srr) * DIM + scc;
  const u16* vbase = Vp + (size_t)(klo + srr) * DIM + scc;
  u16x8 kp0 = *(const u16x8*)kbase;
  u16x8 kp1 = *(const u16x8*)(kbase + 8);
  u16x8 vp0 = *(const u16x8*)vbase;
  u16x8 vp1 = *(const u16x8*)(vbase + 8);

  for (int ti = 0; ti < nt; ++ti) {
    const int kt = klo + ti * 64;
    *(u16x8*)(Ks + srr * 72 + scc) = kp0;
    *(u16x8*)(Ks + srr * 72 + scc + 8) = kp1;
#pragma unroll
    for (int e = 0; e < 8; ++e) {
      Vt[(scc + e) * 72 + vr] = vp0[e];
      Vt[(scc + 8 + e) * 72 + vr] = vp1[e];
    }
    __syncthreads();

    if (ti + 1 < nt) {
      const u16* kn = kbase + (size_t)(ti + 1) * 64 * DIM;
      const u16* vn = vbase + (size_t)(ti + 1) * 64 * DIM;
      kp0 = *(const u16x8*)kn;
      kp1 = *(const u16x8*)(kn + 8);
      vp0 = *(const u16x8*)vn;
      vp1 = *(const u16x8*)(vn + 8);
    }

    f32x4 s[4];
#pragma unroll
    for (int t = 0; t < 4; ++t) {
      const u16* kr = Ks + (t * 16 + c15) * 72 + g * 8;
      bf16x8 ka = *(const bf16x8*)kr;
      bf16x8 kb = *(const bf16x8*)(kr + 32);
      f32x4 z = (f32x4){0.f, 0.f, 0.f, 0.f};
      z = __builtin_amdgcn_mfma_f32_16x16x32_bf16(qf0, ka, z, 0, 0, 0);
      s[t] = __builtin_amdgcn_mfma_f32_16x16x32_bf16(qf1, kb, z, 0, 0, 0);
    }
    if (kt >= r0 - 113 && kt <= r0 + 65) {
#pragma unroll
      for (int j = 0; j < 4; ++j) {
#pragma unroll
        for (int t = 0; t < 4; ++t) {
          const float p = __expf(s[t][j] * 0.125f);
          lrun[j] += p;
          Pl[wid][(g * 4 + j) * 72 + t * 16 + c15] = f2bf(p);
        }
      }
    } else {
#pragma unroll
      for (int j = 0; j < 4; ++j) {
        const int qg = r0 + g * 4 + j;
#pragma unroll
        for (int t = 0; t < 4; ++t) {
          const int kg = kt + t * 16 + c15;
          const int dd = qg - kg;
          const bool ok = (kg == 0) || (dd <= WIN && dd >= -WIN);
          const float p = ok ? __expf(s[t][j] * 0.125f) : 0.f;
          lrun[j] += p;
          Pl[wid][(g * 4 + j) * 72 + t * 16 + c15] = f2bf(p);
        }
      }
    }
    asm volatile("s_waitcnt lgkmcnt(0)" ::: "memory");

    const bf16x8 pa0 = *(const bf16x8*)(&Pl[wid][c15 * 72 + g * 8]);
    const bf16x8 pa1 = *(const bf16x8*)(&Pl[wid][c15 * 72 + 32 + g * 8]);
#pragma unroll
    for (int c = 0; c < 4; ++c) {
      const int rb = (c * 16 + c15) * 72;
      bf16x8 va = *(const bf16x8*)(Vt + rb + ((g * 8) ^ (c << 4)));
      bf16x8 vb = *(const bf16x8*)(Vt + rb + ((32 + g * 8) ^ (c << 4)));
      ao[c] = __builtin_amdgcn_mfma_f32_16x16x32_bf16(pa0, va, ao[c], 0, 0, 0);
      ao[c] = __builtin_amdgcn_mfma_f32_16x16x32_bf16(pa1, vb, ao[c], 0, 0, 0);
    }
    __syncthreads();
  }

  float ltot[4];
#pragma unroll
  for (int j = 0; j < 4; ++j) {
    float ls = lrun[j];
    ls += __shfl_xor(ls, 1);
    ls += __shfl_xor(ls, 2);
    ls += __shfl_xor(ls, 4);
    ls += __shfl_xor(ls, 8);
    ltot[j] = ls;
  }

  if (klo > 0) {
    const u16x8 qu0 = *(const u16x8*)&qf0;
    const u16x8 qu1 = *(const u16x8*)&qf1;
    const u16x8 k0a = *(const u16x8*)(Kp + g * 8);
    const u16x8 k0b = *(const u16x8*)(Kp + 32 + g * 8);
    float sg = 0.f;
#pragma unroll
    for (int e = 0; e < 8; ++e)
      sg += bf2f(qu0[e]) * bf2f(k0a[e]) + bf2f(qu1[e]) * bf2f(k0b[e]);
    sg += __shfl_xor(sg, 16);
    sg += __shfl_xor(sg, 32);
    const float pg = __expf(sg * 0.125f);
    Pg[wid][c15] = pg;
    asm volatile("s_waitcnt lgkmcnt(0)" ::: "memory");
#pragma unroll
    for (int j = 0; j < 4; ++j) {
      const float pj = Pg[wid][g * 4 + j];
      ltot[j] += pj;
#pragma unroll
      for (int c = 0; c < 4; ++c)
        ao[c][j] += pj * bf2f(Vp[c * 16 + c15]);
    }
  }

#pragma unroll
  for (int j = 0; j < 4; ++j) {
    const int qrow = r0 + g * 4 + j;
    if (qrow == 0) continue;
    const float inv = 1.0f / ltot[j];
#pragma unroll
    for (int c = 0; c < 4; ++c)
      AO[ha + (size_t)qrow * DIM + c * 16 + c15] = f2bf(ao[c][j] * inv);
  }
}

// ---------------- launch -----------------------------------------------------
extern "C" void kernel_launch(void* const* d_in, const int* in_sizes, int n_in,
                              void* d_out, int out_size, void* d_ws, size_t ws_size,
                              hipStream_t stream) {
  const float* x  = (const float*)d_in[0];
  const float* Wq = (const float*)d_in[1];
  const float* Wk = (const float*)d_in[2];
  const float* Wv = (const float*)d_in[3];
  const float* Wo = (const float*)d_in[4];
  float* out = (float*)d_out;

  const int WN = DIM * DIM;

  u16* ws  = (u16*)d_ws;
  u16* xb  = ws;                      // bf16 x [4096,1024]; reused as AO
  u16* wb  = ws + (size_t)XN_EL;      // Wq,Wk,Wv,Wo bf16 contiguous
  u16* Wob = wb + (size_t)3 * WN;
  u16* Qb  = wb + (size_t)4 * WN;     // [4096,1024]
  u16* Kb  = Qb + (size_t)XN_EL;      // [4096,1024]
  u16* Vb  = Kb + (size_t)XN_EL;      // [4096,1024]

  cvt_all<<<4096, 256, 0, stream>>>(x, Wq, Wk, Wv, Wo, xb, wb);

  // fused QKV: 256x192 tiles, 8-phase schedule, grid 256 (measured optimum)
  gemm8<<<256, 512, 0, stream>>>(xb, wb, Qb, 16);

  // attention: pair-locked 1-D grid (8 XCDs x 4 heads x 33 blocks)
  sparse_attn<<<1056, 256, 0, stream>>>(Qb, Kb, Vb, xb);

  // output projection: 128x128 tiles, grid 256
  gemm3<128, 128, 2, 2, DIM, float><<<256, 256, 0, stream>>>(xb, Wob, out, 32);
}